// Round 1
// baseline (233.342 us; speedup 1.0000x reference)
//
#include <hip/hip_runtime.h>

#define RANK 16
#define EMBED_DIM 128
#define SCAN_TILE 1024  // 256 threads x 4 items per scan block

// ---------------------------------------------------------------------------
// K1: detect edge_index element width. int64 layout => odd 32-bit words are
// high halves of node ids (< 2^31) => all zero. int32 layout => random node
// ids => essentially surely nonzero. flag=1 means int32.
// ---------------------------------------------------------------------------
__global__ void detect_idx_dtype(const unsigned int* __restrict__ words,
                                 int nwords, int* __restrict__ flag) {
    unsigned int v = 0;
    for (int i = threadIdx.x; i < 2048; i += 256) {
        int w = 2 * i + 1;
        if (w < nwords) v |= words[w];
    }
    if (__any(v != 0)) {
        if ((threadIdx.x & 63) == 0) atomicOr(flag, 1);
    }
}

// ---------------------------------------------------------------------------
// K2: histogram of destination nodes into off[0..N). 1 int atomic per edge
// (vs 17 atomics/edge in the old scatter_rank).
// ---------------------------------------------------------------------------
__global__ void edge_hist(const void* __restrict__ edge_index,
                          int* __restrict__ off,
                          const int* __restrict__ flag, int E) {
    int e = blockIdx.x * 256 + threadIdx.x;
    if (e >= E) return;
    const int* w = (const int*)edge_index;
    int dst = *flag ? w[E + e] : w[2 * (E + e)];
    atomicAdd(&off[dst], 1);
}

// ---------------------------------------------------------------------------
// K3/K4/K5: exclusive prefix sum over off[0..N), in place.
// pass1: per-block (1024 elems) exclusive scan + block sums.
// pass2: single block scans the <=256 block sums.
// pass3: add scanned block sums; also mirror result into cur[] (reorder
//        cursors) and set off[N] = E.
// ---------------------------------------------------------------------------
__global__ __launch_bounds__(256) void scan_pass1(int* __restrict__ off,
                                                  int* __restrict__ bsums,
                                                  int N) {
    __shared__ int lds[256];
    int t = threadIdx.x;
    int base = blockIdx.x * SCAN_TILE + t * 4;
    int c0 = 0, c1 = 0, c2 = 0, c3 = 0;
    if (base + 3 < N) {
        int4 v = *(const int4*)(off + base);
        c0 = v.x; c1 = v.y; c2 = v.z; c3 = v.w;
    } else {
        if (base + 0 < N) c0 = off[base + 0];
        if (base + 1 < N) c1 = off[base + 1];
        if (base + 2 < N) c2 = off[base + 2];
        if (base + 3 < N) c3 = off[base + 3];
    }
    int s = c0 + c1 + c2 + c3;
    lds[t] = s;
    __syncthreads();
    for (int d = 1; d < 256; d <<= 1) {
        int v = (t >= d) ? lds[t - d] : 0;
        __syncthreads();
        lds[t] += v;
        __syncthreads();
    }
    int excl = lds[t] - s;              // exclusive prefix of this thread
    if (t == 255) bsums[blockIdx.x] = lds[255];
    if (base + 3 < N) {
        int4 o;
        o.x = excl;
        o.y = excl + c0;
        o.z = excl + c0 + c1;
        o.w = excl + c0 + c1 + c2;
        *(int4*)(off + base) = o;
    } else {
        if (base + 0 < N) off[base + 0] = excl;
        if (base + 1 < N) off[base + 1] = excl + c0;
        if (base + 2 < N) off[base + 2] = excl + c0 + c1;
        if (base + 3 < N) off[base + 3] = excl + c0 + c1 + c2;
    }
}

__global__ __launch_bounds__(256) void scan_pass2(int* __restrict__ bsums,
                                                  int NB) {
    __shared__ int lds[256];
    int t = threadIdx.x;
    int s = (t < NB) ? bsums[t] : 0;
    lds[t] = s;
    __syncthreads();
    for (int d = 1; d < 256; d <<= 1) {
        int v = (t >= d) ? lds[t - d] : 0;
        __syncthreads();
        lds[t] += v;
        __syncthreads();
    }
    if (t < NB) bsums[t] = lds[t] - s;  // exclusive
}

__global__ void scan_pass3(int* __restrict__ off, int* __restrict__ cur,
                           const int* __restrict__ bsums, int N, int E) {
    int i = blockIdx.x * 256 + threadIdx.x;
    if (i == 0 && blockIdx.x == 0) off[N] = E;
    if (i >= N) return;
    int v = off[i] + bsums[i >> 10];
    off[i] = v;
    cur[i] = v;
}

// ---------------------------------------------------------------------------
// K6: scatter src ids into per-dst segments. 1 int atomic + one 4B write
// per edge.
// ---------------------------------------------------------------------------
__global__ void reorder_edges(const void* __restrict__ edge_index,
                              int* __restrict__ cur, int* __restrict__ ssrc,
                              const int* __restrict__ flag, int E) {
    int e = blockIdx.x * 256 + threadIdx.x;
    if (e >= E) return;
    const int* w = (const int*)edge_index;
    int src, dst;
    if (*flag) {            // int32 layout
        src = w[e];
        dst = w[E + e];
    } else {                // int64 layout (little-endian low words)
        src = w[2 * e];
        dst = w[2 * (E + e)];
    }
    int pos = atomicAdd(&cur[dst], 1);
    ssrc[pos] = src;
}

// ---------------------------------------------------------------------------
// K7: fused atomic-free gather + projection.
// Block = 256 threads handles 32 nodes.
// Phase A: group g (16 lanes, lane j = rank) walks node n's CSR segment,
//          acc += U[src][j]  (64B coalesced row reads, L2/LLC-resident U).
// Phase B: same scheme as old project_out, but Usum comes from LDS:
//          thread (q = t&31, w = t>>5) emits 4 nodes x float4 columns.
// ---------------------------------------------------------------------------
__global__ __launch_bounds__(256) void gather_project(
        const float* __restrict__ U,
        const float* __restrict__ V,
        const int* __restrict__ off,
        const int* __restrict__ ssrc,
        float* __restrict__ out, int N) {
    __shared__ float4 Vs4[RANK * EMBED_DIM / 4];  // 8 KB
    __shared__ float accs[32][RANK];              // 2 KB
    __shared__ float sinv[32];

    int t = threadIdx.x;
    const float4* V4 = (const float4*)V;
    Vs4[t] = V4[t];
    Vs4[t + 256] = V4[t + 256];

    int g = t >> 4;   // node group 0..15
    int j = t & 15;   // rank lane
#pragma unroll
    for (int half = 0; half < 2; ++half) {
        int nd = half * 16 + g;
        int n = blockIdx.x * 32 + nd;
        int o0 = 0, o1 = 0;
        if (n < N) { o0 = off[n]; o1 = off[n + 1]; }
        float acc = 0.f;
        for (int e = o0; e < o1; ++e) {
            int s = ssrc[e];                       // broadcast read
            acc += U[(size_t)s * RANK + j];        // 64B coalesced row
        }
        accs[nd][j] = acc;
        if (j == 0) sinv[nd] = 1.0f / fmaxf((float)(o1 - o0), 1.0f);
    }
    __syncthreads();

    int q = t & 31;   // column group: float4 cols q
    int w = t >> 5;   // 0..7 -> nodes 4w..4w+3
#pragma unroll
    for (int r = 0; r < 4; ++r) {
        int nd = 4 * w + r;
        float4 acc4 = make_float4(0.f, 0.f, 0.f, 0.f);
#pragma unroll
        for (int k = 0; k < RANK; ++k) {
            float a = accs[nd][k];                 // broadcast (2-way: free)
            float4 v = Vs4[k * 32 + q];
            acc4.x = fmaf(a, v.x, acc4.x);
            acc4.y = fmaf(a, v.y, acc4.y);
            acc4.z = fmaf(a, v.z, acc4.z);
            acc4.w = fmaf(a, v.w, acc4.w);
        }
        float s = sinv[nd];
        int n = blockIdx.x * 32 + nd;
        if (n < N)
            ((float4*)out)[(size_t)n * (EMBED_DIM / 4) + q] =
                make_float4(acc4.x * s, acc4.y * s, acc4.z * s, acc4.w * s);
    }
}

extern "C" void kernel_launch(void* const* d_in, const int* in_sizes, int n_in,
                              void* d_out, int out_size, void* d_ws, size_t ws_size,
                              hipStream_t stream) {
    const float* U = (const float*)d_in[0];
    const float* V = (const float*)d_in[1];
    const void* EI = d_in[2];
    float* out = (float*)d_out;

    const int N = in_sizes[0] / RANK;   // 200000
    const int E = in_sizes[2] / 2;      // 640000

    // workspace layout (all int32):
    //   off[N+1] | flag[1] | cur[N] | bsums[256] | ssrc[E]
    // total = 2N + 258 + E ints ~= 4.2 MB (old version used 13.6 MB)
    int* off   = (int*)d_ws;
    int* flag  = off + (N + 1);
    int* cur   = flag + 1;
    int* bsums = cur + N;
    int* ssrc  = bsums + 256;

    // zero hist + flag only (0.8 MB vs 13.6 MB before)
    hipMemsetAsync(d_ws, 0, (size_t)(N + 2) * sizeof(int), stream);

    detect_idx_dtype<<<1, 256, 0, stream>>>((const unsigned int*)EI,
                                            in_sizes[2], flag);

    edge_hist<<<(E + 255) / 256, 256, 0, stream>>>(EI, off, flag, E);

    const int NB = (N + SCAN_TILE - 1) / SCAN_TILE;  // 196 (<= 256 required)
    scan_pass1<<<NB, 256, 0, stream>>>(off, bsums, N);
    scan_pass2<<<1, 256, 0, stream>>>(bsums, NB);
    scan_pass3<<<(N + 255) / 256, 256, 0, stream>>>(off, cur, bsums, N, E);

    reorder_edges<<<(E + 255) / 256, 256, 0, stream>>>(EI, cur, ssrc, flag, E);

    gather_project<<<(N + 31) / 32, 256, 0, stream>>>(U, V, off, ssrc, out, N);
}